// Round 1
// baseline (890.918 us; speedup 1.0000x reference)
//
#include <hip/hip_runtime.h>
#include <hip/hip_bf16.h>
#include <cstdint>
#include <cstddef>

#define EPS_BN 1e-5f
#define LDK 40  // LDS leading-dim stride in ushorts (80B: 2-way bank groups only)

typedef __attribute__((ext_vector_type(8))) __bf16 bf16x8;
typedef __attribute__((ext_vector_type(4))) float f32x4;

__device__ __forceinline__ unsigned short f2b(float f) {
    __hip_bfloat16 h = __float2bfloat16(f);
    return __builtin_bit_cast(unsigned short, h);
}

// ---------------- prep kernels ----------------

__global__ void prep_bn_kernel(const float* __restrict__ g1, const float* __restrict__ b1,
                               const float* __restrict__ m1, const float* __restrict__ v1,
                               const float* __restrict__ g2, const float* __restrict__ b2,
                               const float* __restrict__ m2, const float* __restrict__ v2,
                               const float* __restrict__ g3, const float* __restrict__ b3,
                               const float* __restrict__ m3, const float* __restrict__ v3,
                               float* __restrict__ bias1, float* __restrict__ bias2,
                               float* __restrict__ bias3) {
    int t = blockIdx.x * 256 + threadIdx.x;
    if (t < 256) {
        float inv = g1[t] * rsqrtf(v1[t] + EPS_BN);
        bias1[t] = b1[t] - m1[t] * inv;
    } else if (t < 512) {
        int c = t - 256;
        float inv = g2[c] * rsqrtf(v2[c] + EPS_BN);
        bias2[c] = b2[c] - m2[c] * inv;
    } else if (t < 1536) {
        int c = t - 512;
        float inv = g3[c] * rsqrtf(v3[c] + EPS_BN);
        bias3[c] = b3[c] - m3[c] * inv;
    }
}

// w1: (256,1024,1,1) -> w1b[co][ci] bf16, scaled by inv1[co]
__global__ void repack_w1(const float* __restrict__ w1, const float* __restrict__ g1,
                          const float* __restrict__ v1, unsigned short* __restrict__ w1b) {
    int idx = blockIdx.x * 256 + threadIdx.x;  // < 262144
    int co = idx >> 10;
    float inv = g1[co] * rsqrtf(v1[co] + EPS_BN);
    w1b[idx] = f2b(w1[idx] * inv);
}

// w2: (256,256,3,3) OIHW -> w2r[k9][co][ci] bf16, scaled by inv2[co]
__global__ void repack_w2(const float* __restrict__ w2, const float* __restrict__ g2,
                          const float* __restrict__ v2, unsigned short* __restrict__ w2r) {
    int idx = blockIdx.x * 256 + threadIdx.x;  // < 589824
    int k9 = idx >> 16;
    int rem = idx & 65535;
    int co = rem >> 8;
    int ci = rem & 255;
    float inv = g2[co] * rsqrtf(v2[co] + EPS_BN);
    w2r[idx] = f2b(w2[(co * 256 + ci) * 9 + k9] * inv);
}

// w3: (1024,256,1,1) -> w3b[co][ci] bf16, scaled by inv3[co]
__global__ void repack_w3(const float* __restrict__ w3, const float* __restrict__ g3,
                          const float* __restrict__ v3, unsigned short* __restrict__ w3b) {
    int idx = blockIdx.x * 256 + threadIdx.x;  // < 262144
    int co = idx >> 8;
    float inv = g3[co] * rsqrtf(v3[co] + EPS_BN);
    w3b[idx] = f2b(w3[idx] * inv);
}

// ---------------- MFMA inner step (shared by all GEMMs) ----------------
// As[m][k] stride LDK, Bs[n][k] stride LDK. Wave computes 64x64 as 4x4 MFMA tiles.
// A frag: lane holds A[m=lane&15][k=quad*8+j]; B frag: B[n=lane&15][k=quad*8+j]
// C/D: col=lane&15, row=quad*4+reg.
__device__ __forceinline__ void mfma_step(const unsigned short* As, const unsigned short* Bs,
                                          int aoff, int boff, f32x4 acc[4][4]) {
    bf16x8 a[4], b[4];
#pragma unroll
    for (int i = 0; i < 4; ++i)
        a[i] = *reinterpret_cast<const bf16x8*>(As + aoff + i * 16 * LDK);
#pragma unroll
    for (int j = 0; j < 4; ++j)
        b[j] = *reinterpret_cast<const bf16x8*>(Bs + boff + j * 16 * LDK);
#pragma unroll
    for (int i = 0; i < 4; ++i)
#pragma unroll
        for (int j = 0; j < 4; ++j)
            acc[i][j] = __builtin_amdgcn_mfma_f32_16x16x32_bf16(a[i], b[j], acc[i][j], 0, 0, 0);
}

// ---------------- conv1: 1x1, 1024->256, BN+ReLU, out NHWC bf16 with halo ----------------
// grid (7 ntile, 2 mtile, 64 n), 256 threads
__global__ __launch_bounds__(256) void conv1_kernel(const float* __restrict__ x,
                                                    const unsigned short* __restrict__ w1b,
                                                    const float* __restrict__ bias1,
                                                    unsigned short* __restrict__ in2p) {
    __shared__ unsigned short As[128 * LDK];
    __shared__ unsigned short Bs[128 * LDK];
    const int tid = threadIdx.x;
    const int n = blockIdx.z;
    const int m0 = blockIdx.y * 128;
    const int sp0 = blockIdx.x * 128;
    const int lane = tid & 63, wave = tid >> 6;
    const int wr = wave >> 1, wc = wave & 1;
    const int l15 = lane & 15, quad = lane >> 4;
    const int a_kc = tid & 3;
    const int tcol = tid & 31, trow = tid >> 5;

    const float* xn = x + (size_t)n * 1024 * 784;
    const int spb = sp0 + tcol * 4;
    const bool bvalid = spb < 784;

    f32x4 acc[4][4] = {};
    const int aoff = (wr * 64 + l15) * LDK + quad * 8;
    const int boff = (wc * 64 + l15) * LDK + quad * 8;

    for (int kk = 0; kk < 32; ++kk) {
        const int k0 = kk * 32;
        uint4 av[2];
#pragma unroll
        for (int p = 0; p < 2; ++p) {
            int m = p * 64 + (tid >> 2);
            av[p] = *reinterpret_cast<const uint4*>(w1b + (size_t)(m0 + m) * 1024 + k0 + a_kc * 8);
        }
        float4 bv[4];
#pragma unroll
        for (int p = 0; p < 4; ++p) {
            int ci = p * 8 + trow;
            float4 v = {0.f, 0.f, 0.f, 0.f};
            if (bvalid) v = *reinterpret_cast<const float4*>(xn + (size_t)(k0 + ci) * 784 + spb);
            bv[p] = v;
        }
        __syncthreads();
#pragma unroll
        for (int p = 0; p < 2; ++p) {
            int m = p * 64 + (tid >> 2);
            *reinterpret_cast<uint4*>(As + m * LDK + a_kc * 8) = av[p];
        }
#pragma unroll
        for (int p = 0; p < 4; ++p) {
            int ci = p * 8 + trow;
            Bs[(tcol * 4 + 0) * LDK + ci] = f2b(bv[p].x);
            Bs[(tcol * 4 + 1) * LDK + ci] = f2b(bv[p].y);
            Bs[(tcol * 4 + 2) * LDK + ci] = f2b(bv[p].z);
            Bs[(tcol * 4 + 3) * LDK + ci] = f2b(bv[p].w);
        }
        __syncthreads();
        mfma_step(As, Bs, aoff, boff, acc);
    }

    // epilogue: bias + relu -> bf16, store NHWC with +1 halo offset
    unsigned short* outn = in2p + (size_t)n * 900 * 256;
#pragma unroll
    for (int j = 0; j < 4; ++j) {
        int sp = sp0 + wc * 64 + j * 16 + l15;
        if (sp >= 784) continue;
        int oh = sp / 28, ow = sp % 28;
        unsigned short* dst = outn + ((oh + 1) * 30 + (ow + 1)) * 256;
#pragma unroll
        for (int i = 0; i < 4; ++i) {
            int co = m0 + wr * 64 + i * 16 + quad * 4;
            float4 bia = *reinterpret_cast<const float4*>(bias1 + co);
            f32x4 v = acc[i][j];
            ushort4 o;
            o.x = f2b(fmaxf(v.x + bia.x, 0.f));
            o.y = f2b(fmaxf(v.y + bia.y, 0.f));
            o.z = f2b(fmaxf(v.z + bia.z, 0.f));
            o.w = f2b(fmaxf(v.w + bia.w, 0.f));
            *reinterpret_cast<ushort4*>(dst + co) = o;
        }
    }
}

// ---------------- conv2: 3x3 as 9 shifted K=256 GEMMs, BN+ReLU, out NHWC bf16 ----------------
// grid (7, 2, 64), 256 threads
__global__ __launch_bounds__(256) void conv2_kernel(const unsigned short* __restrict__ in2p,
                                                    const unsigned short* __restrict__ w2r,
                                                    const float* __restrict__ bias2,
                                                    unsigned short* __restrict__ in3) {
    __shared__ unsigned short As[128 * LDK];
    __shared__ unsigned short Bs[128 * LDK];
    const int tid = threadIdx.x;
    const int n = blockIdx.z;
    const int m0 = blockIdx.y * 128;
    const int sp0 = blockIdx.x * 128;
    const int lane = tid & 63, wave = tid >> 6;
    const int wr = wave >> 1, wc = wave & 1;
    const int l15 = lane & 15, quad = lane >> 4;
    const int a_kc = tid & 3;
    const int tcid = tid & 3, tcl = tid >> 2;

    const unsigned short* inn = in2p + (size_t)n * 900 * 256;

    int oh[2], ow[2];
    bool valp[2];
#pragma unroll
    for (int p = 0; p < 2; ++p) {
        int col = sp0 + p * 64 + tcl;
        valp[p] = col < 784;
        int c = valp[p] ? col : 0;
        oh[p] = c / 28;
        ow[p] = c % 28;
    }

    f32x4 acc[4][4] = {};
    const int aoff = (wr * 64 + l15) * LDK + quad * 8;
    const int boff = (wc * 64 + l15) * LDK + quad * 8;

    for (int k9 = 0; k9 < 9; ++k9) {
        const int kh = k9 / 3, kw = k9 % 3;
        const unsigned short* wbase = w2r + (size_t)k9 * 65536;
        for (int cb = 0; cb < 8; ++cb) {
            const int c0 = cb * 32;
            uint4 av[2];
#pragma unroll
            for (int p = 0; p < 2; ++p) {
                int m = p * 64 + (tid >> 2);
                av[p] = *reinterpret_cast<const uint4*>(wbase + (size_t)(m0 + m) * 256 + c0 + a_kc * 8);
            }
            uint4 bvv[2];
#pragma unroll
            for (int p = 0; p < 2; ++p) {
                uint4 v = {0u, 0u, 0u, 0u};
                if (valp[p])
                    v = *reinterpret_cast<const uint4*>(
                        inn + (size_t)((oh[p] + kh) * 30 + ow[p] + kw) * 256 + c0 + tcid * 8);
                bvv[p] = v;
            }
            __syncthreads();
#pragma unroll
            for (int p = 0; p < 2; ++p) {
                int m = p * 64 + (tid >> 2);
                *reinterpret_cast<uint4*>(As + m * LDK + a_kc * 8) = av[p];
            }
#pragma unroll
            for (int p = 0; p < 2; ++p) {
                *reinterpret_cast<uint4*>(Bs + (p * 64 + tcl) * LDK + tcid * 8) = bvv[p];
            }
            __syncthreads();
            mfma_step(As, Bs, aoff, boff, acc);
        }
    }

    // epilogue: bias + relu -> bf16, store NHWC (no halo)
#pragma unroll
    for (int j = 0; j < 4; ++j) {
        int sp = sp0 + wc * 64 + j * 16 + l15;
        if (sp >= 784) continue;
        unsigned short* dst = in3 + ((size_t)n * 784 + sp) * 256;
#pragma unroll
        for (int i = 0; i < 4; ++i) {
            int co = m0 + wr * 64 + i * 16 + quad * 4;
            float4 bia = *reinterpret_cast<const float4*>(bias2 + co);
            f32x4 v = acc[i][j];
            ushort4 o;
            o.x = f2b(fmaxf(v.x + bia.x, 0.f));
            o.y = f2b(fmaxf(v.y + bia.y, 0.f));
            o.z = f2b(fmaxf(v.z + bia.z, 0.f));
            o.w = f2b(fmaxf(v.w + bia.w, 0.f));
            *reinterpret_cast<ushort4*>(dst + co) = o;
        }
    }
}

// ---------------- conv3: 1x1 256->1024, BN + residual + ReLU, out NCHW fp32 ----------------
// grid (7, 8, 64), 256 threads
__global__ __launch_bounds__(256) void conv3_kernel(const unsigned short* __restrict__ in3,
                                                    const unsigned short* __restrict__ w3b,
                                                    const float* __restrict__ bias3,
                                                    const float* __restrict__ x,
                                                    float* __restrict__ out) {
    __shared__ unsigned short As[128 * LDK];
    __shared__ unsigned short Bs[128 * LDK];
    const int tid = threadIdx.x;
    const int n = blockIdx.z;
    const int m0 = blockIdx.y * 128;
    const int sp0 = blockIdx.x * 128;
    const int lane = tid & 63, wave = tid >> 6;
    const int wr = wave >> 1, wc = wave & 1;
    const int l15 = lane & 15, quad = lane >> 4;
    const int a_kc = tid & 3;
    const int tcid = tid & 3, tcl = tid >> 2;

    const unsigned short* inn = in3 + (size_t)n * 784 * 256;

    bool valp[2];
    int colp[2];
#pragma unroll
    for (int p = 0; p < 2; ++p) {
        int col = sp0 + p * 64 + tcl;
        valp[p] = col < 784;
        colp[p] = valp[p] ? col : 0;
    }

    f32x4 acc[4][4] = {};
    const int aoff = (wr * 64 + l15) * LDK + quad * 8;
    const int boff = (wc * 64 + l15) * LDK + quad * 8;

    for (int kk = 0; kk < 8; ++kk) {
        const int k0 = kk * 32;
        uint4 av[2];
#pragma unroll
        for (int p = 0; p < 2; ++p) {
            int m = p * 64 + (tid >> 2);
            av[p] = *reinterpret_cast<const uint4*>(w3b + (size_t)(m0 + m) * 256 + k0 + a_kc * 8);
        }
        uint4 bvv[2];
#pragma unroll
        for (int p = 0; p < 2; ++p) {
            uint4 v = {0u, 0u, 0u, 0u};
            if (valp[p])
                v = *reinterpret_cast<const uint4*>(inn + (size_t)colp[p] * 256 + k0 + tcid * 8);
            bvv[p] = v;
        }
        __syncthreads();
#pragma unroll
        for (int p = 0; p < 2; ++p) {
            int m = p * 64 + (tid >> 2);
            *reinterpret_cast<uint4*>(As + m * LDK + a_kc * 8) = av[p];
        }
#pragma unroll
        for (int p = 0; p < 2; ++p) {
            *reinterpret_cast<uint4*>(Bs + (p * 64 + tcl) * LDK + tcid * 8) = bvv[p];
        }
        __syncthreads();
        mfma_step(As, Bs, aoff, boff, acc);
    }

    // epilogue: bias + residual + relu -> fp32 NCHW
#pragma unroll
    for (int j = 0; j < 4; ++j) {
        int sp = sp0 + wc * 64 + j * 16 + l15;
        if (sp >= 784) continue;
#pragma unroll
        for (int i = 0; i < 4; ++i) {
            int co = m0 + wr * 64 + i * 16 + quad * 4;
            float4 bia = *reinterpret_cast<const float4*>(bias3 + co);
            f32x4 v = acc[i][j];
#pragma unroll
            for (int r = 0; r < 4; ++r) {
                size_t off = ((size_t)n * 1024 + co + r) * 784 + sp;
                float b = (r == 0) ? bia.x : (r == 1) ? bia.y : (r == 2) ? bia.z : bia.w;
                float f = ((r == 0) ? v.x : (r == 1) ? v.y : (r == 2) ? v.z : v.w) + b + x[off];
                out[off] = fmaxf(f, 0.f);
            }
        }
    }
}

// ---------------- launch ----------------

extern "C" void kernel_launch(void* const* d_in, const int* in_sizes, int n_in,
                              void* d_out, int out_size, void* d_ws, size_t ws_size,
                              hipStream_t stream) {
    const float* x  = (const float*)d_in[0];
    const float* w1 = (const float*)d_in[1];
    const float* w2 = (const float*)d_in[2];
    const float* w3 = (const float*)d_in[3];
    const float* g1 = (const float*)d_in[4];
    const float* b1 = (const float*)d_in[5];
    const float* m1 = (const float*)d_in[6];
    const float* v1 = (const float*)d_in[7];
    const float* g2 = (const float*)d_in[8];
    const float* b2 = (const float*)d_in[9];
    const float* m2 = (const float*)d_in[10];
    const float* v2 = (const float*)d_in[11];
    const float* g3 = (const float*)d_in[12];
    const float* b3 = (const float*)d_in[13];
    const float* m3 = (const float*)d_in[14];
    const float* v3 = (const float*)d_in[15];

    char* ws = (char*)d_ws;
    unsigned short* w1b  = (unsigned short*)(ws + 0);         // 524288 B
    unsigned short* w2r  = (unsigned short*)(ws + 524288);    // 1179648 B
    unsigned short* w3b  = (unsigned short*)(ws + 1703936);   // 524288 B
    float* bias1         = (float*)(ws + 2228224);            // 1024 B
    float* bias2         = (float*)(ws + 2229248);            // 1024 B
    float* bias3         = (float*)(ws + 2230272);            // 4096 B
    unsigned short* in2p = (unsigned short*)(ws + 2234368);   // 29491200 B (64*30*30*256 bf16)
    unsigned short* in3  = (unsigned short*)(ws + 31725568);  // 25690112 B (64*784*256 bf16)
    // total: 57415680 B (~57.4 MB)

    // zero the haloed intermediate (ws is re-poisoned to 0xAA before every call)
    hipMemsetAsync(in2p, 0, (size_t)64 * 900 * 256 * 2, stream);

    prep_bn_kernel<<<6, 256, 0, stream>>>(g1, b1, m1, v1, g2, b2, m2, v2, g3, b3, m3, v3,
                                          bias1, bias2, bias3);
    repack_w1<<<1024, 256, 0, stream>>>(w1, g1, v1, w1b);
    repack_w2<<<2304, 256, 0, stream>>>(w2, g2, v2, w2r);
    repack_w3<<<1024, 256, 0, stream>>>(w3, g3, v3, w3b);

    conv1_kernel<<<dim3(7, 2, 64), 256, 0, stream>>>(x, w1b, bias1, in2p);
    conv2_kernel<<<dim3(7, 2, 64), 256, 0, stream>>>(in2p, w2r, bias2, in3);
    conv3_kernel<<<dim3(7, 8, 64), 256, 0, stream>>>(in3, w3b, bias3, x, (float*)d_out);
}